// Round 7
// baseline (1037.600 us; speedup 1.0000x reference)
//
#include <hip/hip_runtime.h>

// RGCNConv: out_i = x_i @ W_root + bias + sum_r mean_{j in N_r(i)} x_j @ W_r
//
// FUSED aggregate+MFMA design:
//   1. sort edges by seg = dst*R + type (XCD-partitioned hist/reorder -> CSR)
//   2. wallt: WallTc[n][k] bf16, k = r*128+din (r<8) | 1024+din (root)
//   3. fused kernel, one block per 128 nodes:
//        per rp in 0..8: build A-tile[128][128] in LDS (rp<8: mean of x[src] rows
//        via CSR gather, reg-accumulated fp32 -> bf16; rp=8: x itself),
//        stage B-tile = WallTc k-window, 4x MFMA k-steps, accumulate in AGPRs.
//        Epilogue: + bias, store out once. No mean buffer, no chunk passes.
//
// R6 bug fixed here: B-tile staging looped j<4 (64 of 128 bytes per half-row)
// leaving half of Bs uninitialized -> NaN through MFMA. Now j<8.

constexpr int D = 128;
constexpr int R = 8;

typedef __bf16 bf16x8 __attribute__((ext_vector_type(8)));
typedef float  f32x4  __attribute__((ext_vector_type(4)));
typedef unsigned short u16x8 __attribute__((ext_vector_type(8)));
typedef unsigned short u16x4 __attribute__((ext_vector_type(4)));

__device__ __forceinline__ unsigned short f2bf(float f) {
    unsigned u = __builtin_bit_cast(unsigned, f);
    u += 0x7FFFu + ((u >> 16) & 1u);          // round-to-nearest-even
    return (unsigned short)(u >> 16);
}

// ---- sort phase (XCD-partitioned: part owns segs with (seg>>4)&7 == part,
//      64B-line-granular so cursor/spack lines are single-partition) ----
__global__ __launch_bounds__(256)
void hist_kernel(const int* __restrict__ dst, const int* __restrict__ et,
                 int* __restrict__ hist, int E) {
    int part   = blockIdx.x & 7;
    int stride = (gridDim.x >> 3) * 256;
    for (int e = (blockIdx.x >> 3) * 256 + threadIdx.x; e < E; e += stride) {
        int seg = dst[e] * R + et[e];
        if (((seg >> 4) & 7) == part) atomicAdd(&hist[seg], 1);
    }
}

__global__ __launch_bounds__(256)
void block_sums_kernel(const int* __restrict__ hs, int* __restrict__ bsum, int n) {
    __shared__ int sh[256];
    int i = blockIdx.x * 256 + threadIdx.x;
    sh[threadIdx.x] = (i < n) ? hs[i] : 0;
    __syncthreads();
    for (int off = 128; off > 0; off >>= 1) {
        if (threadIdx.x < off) sh[threadIdx.x] += sh[threadIdx.x + off];
        __syncthreads();
    }
    if (threadIdx.x == 0) bsum[blockIdx.x] = sh[0];
}

__global__ __launch_bounds__(64)
void scan_bsum_kernel(int* __restrict__ bsum, int nb) {
    int lane = threadIdx.x;
    int carry = 0;
    for (int base = 0; base < nb; base += 64) {
        int i = base + lane;
        int orig = (i < nb) ? bsum[i] : 0;
        int v = orig;
        #pragma unroll
        for (int off = 1; off < 64; off <<= 1) {
            int u = __shfl_up(v, off, 64);
            if (lane >= off) v += u;
        }
        int tot = __shfl(v, 63, 64);
        if (i < nb) bsum[i] = carry + (v - orig);
        carry += tot;
    }
}

__global__ __launch_bounds__(256)
void scan_block_kernel(int* __restrict__ hs, const int* __restrict__ bsum,
                       int* __restrict__ cursor, int n, int E) {
    __shared__ int sh[256];
    int tid = threadIdx.x;
    int i = blockIdx.x * 256 + tid;
    int v = (i < n) ? hs[i] : 0;
    sh[tid] = v;
    __syncthreads();
    for (int off = 1; off < 256; off <<= 1) {
        int u = (tid >= off) ? sh[tid - off] : 0;
        __syncthreads();
        sh[tid] += u;
        __syncthreads();
    }
    int st = bsum[blockIdx.x] + sh[tid] - v;
    if (i < n) { hs[i] = st; cursor[i] = st; }
    if (i == n) hs[n] = E;
}

__global__ __launch_bounds__(256)
void reorder_kernel(const int* __restrict__ src, const int* __restrict__ dst,
                    const int* __restrict__ et, int* __restrict__ cursor,
                    int* __restrict__ spack, int E) {
    int part   = blockIdx.x & 7;
    int stride = (gridDim.x >> 3) * 256;
    for (int e = (blockIdx.x >> 3) * 256 + threadIdx.x; e < E; e += stride) {
        int seg = dst[e] * R + et[e];
        if (((seg >> 4) & 7) == part) {
            int pos = atomicAdd(&cursor[seg], 1);
            spack[pos] = src[e];
        }
    }
}

// ---- WallTc[n][k] bf16: k<1024 -> W[k>>7][k&127][n]; else Wroot[k-1024][n] ----
__global__ __launch_bounds__(256)
void wallt_kernel(const float* __restrict__ Wroot, const float* __restrict__ W,
                  unsigned short* __restrict__ WallTc) {
    int idx = blockIdx.x * 256 + threadIdx.x;
    if (idx >= 128 * 1152) return;
    int n = idx / 1152, k = idx % 1152;
    float v = (k < 1024) ? W[(size_t)(k >> 7) * 16384 + (size_t)(k & 127) * 128 + n]
                         : Wroot[(size_t)(k - 1024) * 128 + n];
    WallTc[idx] = f2bf(v);
}

// ---- fused aggregate + MFMA GEMM ----
__global__ __launch_bounds__(256)
void fused_kernel(const float* __restrict__ x,
                  const unsigned short* __restrict__ WallTc,
                  const int* __restrict__ spack,
                  const int* __restrict__ hstart,
                  const float* __restrict__ bias,
                  float* __restrict__ out, int N) {
    __shared__ unsigned short As[128 * 128];   // 32 KB, XOR-swizzled rows
    __shared__ unsigned short Bs[128 * 128];   // 32 KB

    const int tid  = threadIdx.x;
    const int row0 = blockIdx.x * 128;
    const int lane = tid & 63;
    const int wid  = tid >> 6;
    const int wm   = wid >> 1, wn = wid & 1;   // wave 2x2 grid, 64x64 each
    const int g    = tid >> 5;                 // gather group 0..7
    const int l32  = tid & 31;                 // lane in group (col-quad)
    const int brow = tid >> 1;                 // B-stage row
    const int bhalf = tid & 1;

    f32x4 acc[4][4] = {};

    for (int rp = 0; rp < 9; ++rp) {
        if (rp) __syncthreads();               // all MFMA reads of prev rp done

        // ---- stage B tile: Bs[n][0..127] = WallTc[n][rp*128 ..] ----
        {
            const unsigned short* wsrc = WallTc + (size_t)brow * 1152 + rp * 128 + bhalf * 64;
            const unsigned swz = (brow & 7) << 4;
            char* bdst = (char*)Bs + brow * 256;
            #pragma unroll
            for (int j = 0; j < 8; ++j) {      // 8 x 16B = full 128B half-row
                u16x8 v = *(const u16x8*)(wsrc + j * 8);
                *(u16x8*)(bdst + (((bhalf * 128 + j * 16) ^ swz))) = v;
            }
        }

        // ---- stage A tile ----
        if (rp == 8) {
            #pragma unroll
            for (int nb = 0; nb < 16; ++nb) {
                int nl = nb * 8 + g;
                int node = row0 + nl;
                float4 v = make_float4(0.f, 0.f, 0.f, 0.f);
                if (node < N) v = *(const float4*)(x + (size_t)node * D + l32 * 4);
                u16x4 o;
                o[0] = f2bf(v.x); o[1] = f2bf(v.y); o[2] = f2bf(v.z); o[3] = f2bf(v.w);
                *(u16x4*)((char*)As + nl * 256 + ((l32 * 8) ^ ((nl & 7) << 4))) = o;
            }
        } else {
            int pp0[16], pp1[16];
            #pragma unroll
            for (int nb = 0; nb < 16; ++nb) {       // preload all CSR ranges (ILP)
                int node = row0 + nb * 8 + g;
                if (node < N) {
                    int seg = node * R + rp;
                    pp0[nb] = hstart[seg];
                    pp1[nb] = hstart[seg + 1];
                } else { pp0[nb] = 0; pp1[nb] = 0; }
            }
            #pragma unroll
            for (int nb = 0; nb < 16; ++nb) {
                int nl = nb * 8 + g;
                int p0 = pp0[nb], p1 = pp1[nb];
                float a0 = 0.f, a1 = 0.f, a2 = 0.f, a3 = 0.f;
                for (int p = p0; p < p1; p += 4) {  // 4 edges in flight per chunk
                    int s0 = spack[p];
                    int s1 = (p + 1 < p1) ? spack[p + 1] : -1;
                    int s2 = (p + 2 < p1) ? spack[p + 2] : -1;
                    int s3 = (p + 3 < p1) ? spack[p + 3] : -1;
                    float4 v0 = *(const float4*)(x + ((size_t)s0 << 7) + l32 * 4);
                    a0 += v0.x; a1 += v0.y; a2 += v0.z; a3 += v0.w;
                    if (s1 >= 0) {
                        float4 v = *(const float4*)(x + ((size_t)s1 << 7) + l32 * 4);
                        a0 += v.x; a1 += v.y; a2 += v.z; a3 += v.w;
                    }
                    if (s2 >= 0) {
                        float4 v = *(const float4*)(x + ((size_t)s2 << 7) + l32 * 4);
                        a0 += v.x; a1 += v.y; a2 += v.z; a3 += v.w;
                    }
                    if (s3 >= 0) {
                        float4 v = *(const float4*)(x + ((size_t)s3 << 7) + l32 * 4);
                        a0 += v.x; a1 += v.y; a2 += v.z; a3 += v.w;
                    }
                }
                float inv = (p1 > p0) ? 1.0f / (float)(p1 - p0) : 0.0f;
                u16x4 o;
                o[0] = f2bf(a0 * inv); o[1] = f2bf(a1 * inv);
                o[2] = f2bf(a2 * inv); o[3] = f2bf(a3 * inv);
                *(u16x4*)((char*)As + nl * 256 + ((l32 * 8) ^ ((nl & 7) << 4))) = o;
            }
        }
        __syncthreads();

        // ---- MFMA: 4 k-steps of 32 over this rp's 128-col window ----
        const int rl = lane & 15;
        const int kb = (lane >> 4) * 16;       // byte offset of k-octet
        #pragma unroll
        for (int kt = 0; kt < 4; ++kt) {
            bf16x8 av[4], bv[4];
            #pragma unroll
            for (int f = 0; f < 4; ++f) {
                int ar = wm * 64 + f * 16 + rl;
                av[f] = __builtin_bit_cast(bf16x8,
                    *(const u16x8*)((const char*)As + ar * 256 + ((kt * 64 + kb) ^ ((ar & 7) << 4))));
                int br = wn * 64 + f * 16 + rl;
                bv[f] = __builtin_bit_cast(bf16x8,
                    *(const u16x8*)((const char*)Bs + br * 256 + ((kt * 64 + kb) ^ ((br & 7) << 4))));
            }
            #pragma unroll
            for (int mf = 0; mf < 4; ++mf)
                #pragma unroll
                for (int nf = 0; nf < 4; ++nf)
                    acc[mf][nf] = __builtin_amdgcn_mfma_f32_16x16x32_bf16(av[mf], bv[nf],
                                                                         acc[mf][nf], 0, 0, 0);
        }
    }

    // ---- epilogue: + bias, single store ----
    const int rl = lane & 15;
    const int rg = lane >> 4;
    #pragma unroll
    for (int nf = 0; nf < 4; ++nf) {
        int n = wn * 64 + nf * 16 + rl;
        float bb = bias[n];
        #pragma unroll
        for (int mf = 0; mf < 4; ++mf) {
            #pragma unroll
            for (int i = 0; i < 4; ++i) {
                int nd = row0 + wm * 64 + mf * 16 + rg * 4 + i;
                if (nd < N) out[(size_t)nd * D + n] = acc[mf][nf][i] + bb;
            }
        }
    }
}

extern "C" void kernel_launch(void* const* d_in, const int* in_sizes, int n_in,
                              void* d_out, int out_size, void* d_ws, size_t ws_size,
                              hipStream_t stream) {
    const float* x     = (const float*)d_in[0];
    const float* W     = (const float*)d_in[1];
    const float* Wroot = (const float*)d_in[2];
    const float* bias  = (const float*)d_in[3];
    const int*   ei    = (const int*)d_in[4];
    const int*   et    = (const int*)d_in[5];
    float*       out   = (float*)d_out;

    const int N = in_sizes[0] / D;
    const int E = in_sizes[5];
    const int* src = ei;
    const int* dst = ei + E;

    const int NSEG = N * R;
    const int NB   = (NSEG + 256) / 256;

    const size_t walltc_bytes = (size_t)128 * 1152 * 2;   // 294912, 16B-aligned
    const size_t need = walltc_bytes + ((size_t)(NSEG + 1) + NSEG + E + NB) * 4 + 256;
    if (ws_size < need) return;

    char* p = (char*)d_ws;
    unsigned short* WallTc = (unsigned short*)p;  p += walltc_bytes;
    int* hstart = (int*)p;  p += (size_t)(NSEG + 1) * 4;
    int* cursor = (int*)p;  p += (size_t)NSEG * 4;
    int* spack  = (int*)p;  p += (size_t)E * 4;
    int* bsum   = (int*)p;

    hipMemsetAsync(hstart, 0, (size_t)(NSEG + 1) * 4, stream);

    wallt_kernel<<<(128 * 1152 + 255) / 256, 256, 0, stream>>>(Wroot, W, WallTc);

    hist_kernel<<<8 * 80, 256, 0, stream>>>(dst, et, hstart, E);
    block_sums_kernel<<<NB, 256, 0, stream>>>(hstart, bsum, NSEG);
    scan_bsum_kernel<<<1, 64, 0, stream>>>(bsum, NB);
    scan_block_kernel<<<NB, 256, 0, stream>>>(hstart, bsum, cursor, NSEG, E);
    reorder_kernel<<<8 * 80, 256, 0, stream>>>(src, dst, et, cursor, spack, E);

    const int gx = (N + 127) / 128;
    fused_kernel<<<gx, 256, 0, stream>>>(x, WallTc, spack, hstart, bias, out, N);
}

// Round 8
// 416.881 us; speedup vs baseline: 2.4890x; 2.4890x over previous
//
#include <hip/hip_runtime.h>

// RGCNConv: out_i = x_i @ W_root + bias + sum_r mean_{j in N_r(i)} x_j @ W_r
//
// R8: high-occupancy separate kernels (R5 skeleton), gather from bf16 x:
//   0. xbf = bf16(x)                      (25.6 MB, cache-hot for gathers)
//   1. sort edges by seg = dst*R+type     (XCD-partitioned hist/reorder)
//   2. aggregate: mean_bf[seg][CW] = bf16(mean of xbf[src] cols)  (fp32 accum)
//   3. MFMA GEMM: out[N,128] (+)= [xbf | mean_bf] @ WallT_bf (+bias)
//   CW=128 single-pass when ws allows (aggregate working set now ~231 MB:
//   xbf 25.6 hot + mean 205 streaming); else CW=64/32 multi-pass.

constexpr int D = 128;
constexpr int R = 8;

typedef __bf16 bf16x8 __attribute__((ext_vector_type(8)));
typedef float  f32x4  __attribute__((ext_vector_type(4)));
typedef unsigned short u16x8 __attribute__((ext_vector_type(8)));
typedef unsigned short u16x4 __attribute__((ext_vector_type(4)));

__device__ __forceinline__ unsigned short f2bf(float f) {
    unsigned u = __builtin_bit_cast(unsigned, f);
    u += 0x7FFFu + ((u >> 16) & 1u);          // round-to-nearest-even
    return (unsigned short)(u >> 16);
}

// ---- phase 0: x -> bf16 ----
__global__ __launch_bounds__(256)
void xbf_kernel(const float* __restrict__ x, unsigned short* __restrict__ xbf, int nquad) {
    int stride = gridDim.x * 256;
    for (int i = blockIdx.x * 256 + threadIdx.x; i < nquad; i += stride) {
        float4 v = ((const float4*)x)[i];
        u16x4 o;
        o[0] = f2bf(v.x); o[1] = f2bf(v.y); o[2] = f2bf(v.z); o[3] = f2bf(v.w);
        ((u16x4*)xbf)[i] = o;
    }
}

// ---- sort phase (XCD-partitioned: part owns segs with (seg>>4)&7 == part) ----
__global__ __launch_bounds__(256)
void hist_kernel(const int* __restrict__ dst, const int* __restrict__ et,
                 int* __restrict__ hist, int E) {
    int part   = blockIdx.x & 7;
    int stride = (gridDim.x >> 3) * 256;
    for (int e = (blockIdx.x >> 3) * 256 + threadIdx.x; e < E; e += stride) {
        int seg = dst[e] * R + et[e];
        if (((seg >> 4) & 7) == part) atomicAdd(&hist[seg], 1);
    }
}

__global__ __launch_bounds__(256)
void block_sums_kernel(const int* __restrict__ hs, int* __restrict__ bsum, int n) {
    __shared__ int sh[256];
    int i = blockIdx.x * 256 + threadIdx.x;
    sh[threadIdx.x] = (i < n) ? hs[i] : 0;
    __syncthreads();
    for (int off = 128; off > 0; off >>= 1) {
        if (threadIdx.x < off) sh[threadIdx.x] += sh[threadIdx.x + off];
        __syncthreads();
    }
    if (threadIdx.x == 0) bsum[blockIdx.x] = sh[0];
}

__global__ __launch_bounds__(64)
void scan_bsum_kernel(int* __restrict__ bsum, int nb) {
    int lane = threadIdx.x;
    int carry = 0;
    for (int base = 0; base < nb; base += 64) {
        int i = base + lane;
        int orig = (i < nb) ? bsum[i] : 0;
        int v = orig;
        #pragma unroll
        for (int off = 1; off < 64; off <<= 1) {
            int u = __shfl_up(v, off, 64);
            if (lane >= off) v += u;
        }
        int tot = __shfl(v, 63, 64);
        if (i < nb) bsum[i] = carry + (v - orig);
        carry += tot;
    }
}

__global__ __launch_bounds__(256)
void scan_block_kernel(int* __restrict__ hs, const int* __restrict__ bsum,
                       int* __restrict__ cursor, int n, int E) {
    __shared__ int sh[256];
    int tid = threadIdx.x;
    int i = blockIdx.x * 256 + tid;
    int v = (i < n) ? hs[i] : 0;
    sh[tid] = v;
    __syncthreads();
    for (int off = 1; off < 256; off <<= 1) {
        int u = (tid >= off) ? sh[tid - off] : 0;
        __syncthreads();
        sh[tid] += u;
        __syncthreads();
    }
    int st = bsum[blockIdx.x] + sh[tid] - v;
    if (i < n) { hs[i] = st; cursor[i] = st; }
    if (i == n) hs[n] = E;
}

__global__ __launch_bounds__(256)
void reorder_kernel(const int* __restrict__ src, const int* __restrict__ dst,
                    const int* __restrict__ et, int* __restrict__ cursor,
                    int* __restrict__ spack, int E) {
    int part   = blockIdx.x & 7;
    int stride = (gridDim.x >> 3) * 256;
    for (int e = (blockIdx.x >> 3) * 256 + threadIdx.x; e < E; e += stride) {
        int seg = dst[e] * R + et[e];
        if (((seg >> 4) & 7) == part) {
            int pos = atomicAdd(&cursor[seg], 1);
            spack[pos] = src[e];
        }
    }
}

// ---- aggregate: mean_bf[seg][CW], gathering bf16 rows, fp32 accumulate ----
// tshift = log2(CW/8); each thread owns 8 cols (one u16x8 = 16B per edge).
__global__ __launch_bounds__(256)
void aggregate_kernel(const unsigned short* __restrict__ xbf,
                      const int* __restrict__ spack,
                      const int* __restrict__ hstart,
                      unsigned short* __restrict__ mean,
                      int nseg, int tshift, int c0) {
    int idx = blockIdx.x * 256 + threadIdx.x;
    int seg = idx >> tshift;
    int c8  = idx & ((1 << tshift) - 1);
    if (seg >= nseg) return;
    int p0 = hstart[seg], p1 = hstart[seg + 1];
    int coff = c0 + c8 * 8;
    float a[8] = {};
    for (int p = p0; p < p1; ++p) {
        int s = spack[p];
        u16x8 v = *(const u16x8*)(xbf + ((size_t)s << 7) + coff);
        #pragma unroll
        for (int j = 0; j < 8; ++j)
            a[j] += __builtin_bit_cast(float, (unsigned)v[j] << 16);
    }
    float inv = (p1 > p0) ? 1.0f / (float)(p1 - p0) : 0.0f;
    u16x8 o;
    #pragma unroll
    for (int j = 0; j < 8; ++j) o[j] = f2bf(a[j] * inv);
    *(u16x8*)(mean + ((size_t)seg << (tshift + 3)) + c8 * 8) = o;
}

// ---- WallTc[n][kk] bf16 for one pass ----
// first: kk<128 -> Wroot[kk][n]; else lk=kk-128*first, r=lk/CW, cc=lk%CW -> W[r][c0+cc][n]
__global__ __launch_bounds__(256)
void wallt_kernel(const float* __restrict__ Wroot, const float* __restrict__ W,
                  unsigned short* __restrict__ WallTc, int KW, int CW, int c0, int first) {
    int idx = blockIdx.x * 256 + threadIdx.x;
    if (idx >= 128 * KW) return;
    int n = idx / KW, kk = idx % KW;
    float v;
    if (first && kk < 128) {
        v = Wroot[kk * 128 + n];
    } else {
        int lk = kk - (first ? 128 : 0);
        int r = lk / CW, cc = lk % CW;
        v = W[((size_t)r * 128 + c0 + cc) * 128 + n];
    }
    WallTc[idx] = f2bf(v);
}

// ---- MFMA GEMM: out[128-tile][128] (+)= [xbf | mean] @ WallTc ----
template<bool FIRST>
__global__ __launch_bounds__(256)
void mfma_gemm_kernel(const unsigned short* __restrict__ xbf,
                      const unsigned short* __restrict__ mean,
                      const unsigned short* __restrict__ WallTc,
                      const float* __restrict__ bias,
                      float* __restrict__ out,
                      int N, int NT, int KW, int MROW) {
    __shared__ unsigned short As[128][32];
    __shared__ unsigned short Bs[128][32];
    const int tid  = threadIdx.x;
    const int row0 = blockIdx.x * 128;
    const int lane = tid & 63;
    const int wid  = tid >> 6;
    const int wm   = wid >> 1;         // wave grid 2x2, each wave 64x64
    const int wn   = wid & 1;
    const int srow = tid >> 1;         // staging row 0..127
    const int sh16 = (tid & 1) * 16;   // staging k-offset (elems)

    f32x4 acc[4][4] = {};

    const int  node = row0 + srow;
    const bool nok  = node < N;

    for (int kt = 0; kt < NT; ++kt) {
        if (kt) __syncthreads();
        u16x8 a0, a1;
        #pragma unroll
        for (int j = 0; j < 8; ++j) { a0[j] = 0; a1[j] = 0; }
        if (FIRST && kt < 4) {
            if (nok) {
                const u16x8* xp = (const u16x8*)(xbf + ((size_t)node << 7) + kt * 32 + sh16);
                a0 = xp[0]; a1 = xp[1];
            }
        } else {
            if (nok) {
                const u16x8* mp = (const u16x8*)(mean + (size_t)node * MROW
                                                 + (kt - (FIRST ? 4 : 0)) * 32 + sh16);
                a0 = mp[0]; a1 = mp[1];
            }
        }
        const u16x8* wp = (const u16x8*)(WallTc + (size_t)srow * KW + kt * 32 + sh16);
        u16x8 b0 = wp[0], b1 = wp[1];

        *(u16x8*)&As[srow][sh16]     = a0;
        *(u16x8*)&As[srow][sh16 + 8] = a1;
        *(u16x8*)&Bs[srow][sh16]     = b0;
        *(u16x8*)&Bs[srow][sh16 + 8] = b1;
        __syncthreads();

        const int kg = (lane >> 4) * 8;
        const int rl = lane & 15;
        bf16x8 av[4], bv[4];
        #pragma unroll
        for (int f = 0; f < 4; ++f) {
            av[f] = __builtin_bit_cast(bf16x8, *(const u16x8*)&As[wm * 64 + f * 16 + rl][kg]);
            bv[f] = __builtin_bit_cast(bf16x8, *(const u16x8*)&Bs[wn * 64 + f * 16 + rl][kg]);
        }
        #pragma unroll
        for (int mf = 0; mf < 4; ++mf)
            #pragma unroll
            for (int nf = 0; nf < 4; ++nf)
                acc[mf][nf] = __builtin_amdgcn_mfma_f32_16x16x32_bf16(av[mf], bv[nf],
                                                                     acc[mf][nf], 0, 0, 0);
    }

    const int rl = lane & 15;
    const int rg = lane >> 4;
    #pragma unroll
    for (int nf = 0; nf < 4; ++nf) {
        int n = wn * 64 + nf * 16 + rl;
        float bb = FIRST ? bias[n] : 0.0f;
        #pragma unroll
        for (int mf = 0; mf < 4; ++mf) {
            #pragma unroll
            for (int i = 0; i < 4; ++i) {
                int nd = row0 + wm * 64 + mf * 16 + rg * 4 + i;
                if (nd < N) {
                    size_t o = (size_t)nd * 128 + n;
                    if (FIRST) out[o] = acc[mf][nf][i] + bb;
                    else       out[o] += acc[mf][nf][i];
                }
            }
        }
    }
}

extern "C" void kernel_launch(void* const* d_in, const int* in_sizes, int n_in,
                              void* d_out, int out_size, void* d_ws, size_t ws_size,
                              hipStream_t stream) {
    const float* x     = (const float*)d_in[0];
    const float* W     = (const float*)d_in[1];
    const float* Wroot = (const float*)d_in[2];
    const float* bias  = (const float*)d_in[3];
    const int*   ei    = (const int*)d_in[4];
    const int*   et    = (const int*)d_in[5];
    float*       out   = (float*)d_out;

    const int N = in_sizes[0] / D;
    const int E = in_sizes[5];
    const int* src = ei;
    const int* dst = ei + E;

    const int NSEG = N * R;
    const int NB   = (NSEG + 256) / 256;

    const size_t xbf_bytes    = (size_t)N * D * 2;
    const size_t walltc_bytes = (size_t)128 * 1152 * 2;
    const size_t fixed_bytes  = xbf_bytes + walltc_bytes +
                                ((size_t)(NSEG + 1) + NSEG + E + NB) * 4 + 256;

    // largest CW that fits: 128 -> single pass (no out-RMW), else 64/32
    int CW = 0, tshift = 0;
    const int cands[3]   = {128, 64, 32};
    const int tshifts[3] = {4, 3, 2};
    for (int i = 0; i < 3; ++i) {
        size_t need = (size_t)NSEG * cands[i] * 2 + fixed_bytes;
        if (need <= ws_size) { CW = cands[i]; tshift = tshifts[i]; break; }
    }
    if (CW == 0) return;

    char* p = (char*)d_ws;
    unsigned short* mean   = (unsigned short*)p;  p += (size_t)NSEG * CW * 2;
    unsigned short* xbf    = (unsigned short*)p;  p += xbf_bytes;
    unsigned short* WallTc = (unsigned short*)p;  p += walltc_bytes;
    int* hstart = (int*)p;  p += (size_t)(NSEG + 1) * 4;
    int* cursor = (int*)p;  p += (size_t)NSEG * 4;
    int* spack  = (int*)p;  p += (size_t)E * 4;
    int* bsum   = (int*)p;

    hipMemsetAsync(hstart, 0, (size_t)(NSEG + 1) * 4, stream);

    xbf_kernel<<<2048, 256, 0, stream>>>(x, xbf, N * D / 4);

    hist_kernel<<<8 * 80, 256, 0, stream>>>(dst, et, hstart, E);
    block_sums_kernel<<<NB, 256, 0, stream>>>(hstart, bsum, NSEG);
    scan_bsum_kernel<<<1, 64, 0, stream>>>(bsum, NB);
    scan_block_kernel<<<NB, 256, 0, stream>>>(hstart, bsum, cursor, NSEG, E);
    reorder_kernel<<<8 * 80, 256, 0, stream>>>(src, dst, et, cursor, spack, E);

    const int gx  = (N + 127) / 128;
    const int nch = D / CW;
    for (int c = 0; c < nch; ++c) {
        int c0    = c * CW;
        int first = (c == 0);
        long long aggth = (long long)NSEG << tshift;
        aggregate_kernel<<<(int)((aggth + 255) / 256), 256, 0, stream>>>(
            xbf, spack, hstart, mean, NSEG, tshift, c0);
        int KW   = (first ? 128 : 0) + R * CW;
        int NT   = KW / 32;
        int MROW = R * CW;
        wallt_kernel<<<(128 * KW + 255) / 256, 256, 0, stream>>>(
            Wroot, W, WallTc, KW, CW, c0, first);
        if (first)
            mfma_gemm_kernel<true><<<gx, 256, 0, stream>>>(
                xbf, mean, WallTc, bias, out, N, NT, KW, MROW);
        else
            mfma_gemm_kernel<false><<<gx, 256, 0, stream>>>(
                xbf, mean, WallTc, bias, out, N, NT, KW, MROW);
    }
}